// Round 2
// baseline (847.431 us; speedup 1.0000x reference)
//
#include <hip/hip_runtime.h>

#define NROW 262144
#define DDIM 256
#define KCODE 1024
#define BM 128
#define GBLK (NROW / BM)  // 2048

typedef _Float16 f16x8 __attribute__((ext_vector_type(8)));
typedef _Float16 f16x4 __attribute__((ext_vector_type(4)));
typedef float f32x4 __attribute__((ext_vector_type(4)));

// ---------------------------------------------------------------------------
// prep: split codebook into fp16 hi/lo in MFMA-B-fragment-major layout + norms
// packed half index = ((g*8 + ks)*64 + lane)*8 + sub
//   g = code>>4, lane = (code&15) | (((d>>3)&3)<<4), ks = d>>5, sub = d&7
// ---------------------------------------------------------------------------
__global__ __launch_bounds__(256) void vq_prep(const float* __restrict__ cb,
                                               float* __restrict__ c2,
                                               _Float16* __restrict__ chi,
                                               _Float16* __restrict__ clo) {
  const int code = blockIdx.x;   // 1024
  const int dd = threadIdx.x;    // 256
  const float x = cb[code * DDIM + dd];
  const _Float16 h = (_Float16)x;
  const _Float16 l = (_Float16)(x - (float)h);
  const int g = code >> 4;
  const int ks = dd >> 5;
  const int dsub = (dd >> 3) & 3;
  const int sub = dd & 7;
  const int ln = (code & 15) | (dsub << 4);
  const size_t off = ((((size_t)g * 8 + ks) * 64 + ln) * 8) + sub;
  chi[off] = h;
  clo[off] = l;
  float s = x * x;
  for (int o = 32; o; o >>= 1) s += __shfl_down(s, o);
  __shared__ float w4[4];
  if ((threadIdx.x & 63) == 0) w4[threadIdx.x >> 6] = s;
  __syncthreads();
  if (threadIdx.x == 0) c2[code] = (w4[0] + w4[1]) + (w4[2] + w4[3]);
}

// ---------------------------------------------------------------------------
// main: distances via fp16x3 split MFMA + fused argmin.
// 512 thr = 8 waves (wr 0..1 x wc 0..3), wave tile 64 rows x 64 codes.
// A (z hi/lo) in LDS, XOR-swizzled; B streamed from global (L1/L2-resident).
// idx written as FLOAT values (harness compares integer outputs as f32).
// ---------------------------------------------------------------------------
__global__ __launch_bounds__(512) void vq_gemm_argmin(
    const float* __restrict__ z, const _Float16* __restrict__ chi,
    const _Float16* __restrict__ clo, const float* __restrict__ c2,
    float* __restrict__ out_idx) {
  __shared__ unsigned short Ahi[BM * DDIM];  // fp16 bits, 64 KiB
  __shared__ unsigned short Alo[BM * DDIM];  // 64 KiB
  __shared__ float z2s[BM];
  __shared__ float s_bv[4][BM];
  __shared__ int s_bi[4][BM];

  const int t = threadIdx.x;
  const int ln = t & 63;
  const int wid = t >> 6;
  const int wr = wid >> 2;  // 0..1 row half (64 rows)
  const int wc = wid & 3;   // 0..3 code quarter (64 codes per ct)

  char* ph = (char*)Ahi;
  char* pl = (char*)Alo;

  // ---- stage A: global fp32 -> LDS fp16 hi/lo (swizzled) ----
  {
    const float* zb = z + (size_t)blockIdx.x * (BM * DDIM);
#pragma unroll
    for (int i = 0; i < 16; ++i) {
      const int fi = (i * 512 + t) * 4;  // flat float index in tile
      const int row = fi >> 8;
      const int d = fi & 255;
      const float4 v = *(const float4*)(zb + fi);
      const _Float16 h0 = (_Float16)v.x, h1 = (_Float16)v.y;
      const _Float16 h2 = (_Float16)v.z, h3 = (_Float16)v.w;
      f16x4 hv = {h0, h1, h2, h3};
      f16x4 lv = {(_Float16)(v.x - (float)h0), (_Float16)(v.y - (float)h1),
                  (_Float16)(v.z - (float)h2), (_Float16)(v.w - (float)h3)};
      const int off = (row * 512 + d * 2) ^ ((row & 7) << 4);
      *(f16x4*)(ph + off) = hv;
      *(f16x4*)(pl + off) = lv;
    }
  }
  __syncthreads();

  // ---- z2 per row (hi+lo reconstruction, ~22-bit accurate) ----
  {
    const int row = t >> 2, part = t & 3;
    float s = 0.f;
#pragma unroll
    for (int i = 0; i < 16; ++i) {
      const int d = part * 64 + i * 4;
      const int off = (row * 512 + d * 2) ^ ((row & 7) << 4);
      f16x4 hv = *(const f16x4*)(ph + off);
      f16x4 lv = *(const f16x4*)(pl + off);
#pragma unroll
      for (int j = 0; j < 4; ++j) {
        const float xx = (float)hv[j] + (float)lv[j];
        s = fmaf(xx, xx, s);
      }
    }
    s += __shfl_xor(s, 1);
    s += __shfl_xor(s, 2);
    if (part == 0) z2s[row] = s;
  }
  __syncthreads();

  const int kg = ln >> 4;                 // 0..3
  const int arow0 = wr * 64 + (ln & 15);  // + m*16
  float z2r[4][4];
#pragma unroll
  for (int m = 0; m < 4; ++m)
#pragma unroll
    for (int r = 0; r < 4; ++r)
      z2r[m][r] = z2s[wr * 64 + m * 16 + kg * 4 + r];

  float bestv[4][4];
  int besti[4][4];
#pragma unroll
  for (int m = 0; m < 4; ++m)
#pragma unroll
    for (int r = 0; r < 4; ++r) {
      bestv[m][r] = 3.4e38f;
      besti[m][r] = 0;
    }

  const int swz = (arow0 & 7) << 4;       // m*16 preserves row&7
  const int abase = arow0 * 512 + kg * 16;
  const _Float16* bh0 = chi + (size_t)(wc * 4) * 4096 + (size_t)ln * 8;
  const _Float16* bl0 = clo + (size_t)(wc * 4) * 4096 + (size_t)ln * 8;

  for (int ct = 0; ct < 4; ++ct) {
    f32x4 acc[4][4];
#pragma unroll
    for (int m = 0; m < 4; ++m)
#pragma unroll
      for (int f = 0; f < 4; ++f) acc[m][f] = (f32x4){0.f, 0.f, 0.f, 0.f};

    const _Float16* bh = bh0 + (size_t)ct * (16 * 4096);
    const _Float16* bl = bl0 + (size_t)ct * (16 * 4096);

#pragma unroll 2
    for (int ks = 0; ks < 8; ++ks) {
      f16x8 ah[4], al[4];
#pragma unroll
      for (int m = 0; m < 4; ++m) {
        const int off = (abase + m * 8192 + ks * 64) ^ swz;
        ah[m] = *(const f16x8*)(ph + off);
        al[m] = *(const f16x8*)(pl + off);
      }
      f16x8 bhf[4], blf[4];
#pragma unroll
      for (int f = 0; f < 4; ++f) {
        bhf[f] = *(const f16x8*)(bh + f * 4096 + ks * 512);
        blf[f] = *(const f16x8*)(bl + f * 4096 + ks * 512);
      }
#pragma unroll
      for (int m = 0; m < 4; ++m)
#pragma unroll
        for (int f = 0; f < 4; ++f) {
          acc[m][f] = __builtin_amdgcn_mfma_f32_16x16x32_f16(ah[m], bhf[f], acc[m][f], 0, 0, 0);
          acc[m][f] = __builtin_amdgcn_mfma_f32_16x16x32_f16(ah[m], blf[f], acc[m][f], 0, 0, 0);
          acc[m][f] = __builtin_amdgcn_mfma_f32_16x16x32_f16(al[m], bhf[f], acc[m][f], 0, 0, 0);
        }
    }

    // epilogue: d = (z2 + c2) - 2*dot (replicates reference rounding), argmin
#pragma unroll
    for (int f = 0; f < 4; ++f) {
      const int code = ct * 256 + wc * 64 + f * 16 + (ln & 15);
      const float c2v = c2[code];
#pragma unroll
      for (int m = 0; m < 4; ++m)
#pragma unroll
        for (int r = 0; r < 4; ++r) {
          const float dv = (z2r[m][r] + c2v) - 2.0f * acc[m][f][r];
          if (dv < bestv[m][r]) {  // strict <: first index wins on ties
            bestv[m][r] = dv;
            besti[m][r] = code;
          }
        }
    }
  }

  // cross-lane argmin within each 16-lane col group (tie -> smaller index)
#pragma unroll
  for (int m = 0; m < 4; ++m)
#pragma unroll
    for (int r = 0; r < 4; ++r) {
      float v = bestv[m][r];
      int bi = besti[m][r];
#pragma unroll
      for (int s = 1; s < 16; s <<= 1) {
        const float ov = __shfl_xor(v, s);
        const int oi = __shfl_xor(bi, s);
        if (ov < v || (ov == v && oi < bi)) {
          v = ov;
          bi = oi;
        }
      }
      bestv[m][r] = v;
      besti[m][r] = bi;
    }

  if ((ln & 15) == 0) {
#pragma unroll
    for (int m = 0; m < 4; ++m)
#pragma unroll
      for (int r = 0; r < 4; ++r) {
        const int row = wr * 64 + m * 16 + kg * 4 + r;
        s_bv[wc][row] = bestv[m][r];
        s_bi[wc][row] = besti[m][r];
      }
  }
  __syncthreads();

  if (t < BM) {
    float bv = s_bv[0][t];
    int bi = s_bi[0][t];
#pragma unroll
    for (int q = 1; q < 4; ++q) {
      const float v = s_bv[q][t];
      const int i2 = s_bi[q][t];
      if (v < bv || (v == bv && i2 < bi)) {
        bv = v;
        bi = i2;
      }
    }
    // harness compares integer reference outputs as float32 VALUES
    out_idx[(size_t)blockIdx.x * BM + t] = (float)bi;
  }
}

// ---------------------------------------------------------------------------
// gather: z_q_st = z + (q - z) (exact fp op order), per-block loss partials.
// idx arrives as float32 (exact for < 2^24), convert back to int.
// ---------------------------------------------------------------------------
__global__ __launch_bounds__(256) void vq_gather(const float* __restrict__ z,
                                                 const float* __restrict__ cb,
                                                 const float* __restrict__ idxf,
                                                 float* __restrict__ zq,
                                                 double* __restrict__ partials) {
  const int t = threadIdx.x;
  double local = 0.0;
  for (int i = 0; i < 16; ++i) {
    const size_t c4 = ((size_t)i * 4096 + blockIdx.x) * 256 + t;
    const size_t fi = c4 * 4;
    const int row = (int)(fi >> 8);
    const int code = (int)idxf[row];
    const float4 q = *(const float4*)(cb + (size_t)code * DDIM + (int)(fi & 255));
    const float4 zz = *(const float4*)(z + fi);
    const float d0 = q.x - zz.x, d1 = q.y - zz.y;
    const float d2 = q.z - zz.z, d3 = q.w - zz.w;
    zq[fi] = zz.x + d0;      // scalar stores: zq is off-by-1-float aligned
    zq[fi + 1] = zz.y + d1;
    zq[fi + 2] = zz.z + d2;
    zq[fi + 3] = zz.w + d3;
    local += (double)(d0 * d0 + d1 * d1 + d2 * d2 + d3 * d3);
  }
  for (int o = 32; o; o >>= 1) local += __shfl_down(local, o);
  __shared__ double w4[4];
  if ((t & 63) == 0) w4[t >> 6] = local;
  __syncthreads();
  if (t == 0) partials[blockIdx.x] = (w4[0] + w4[1]) + (w4[2] + w4[3]);
}

// ---------------------------------------------------------------------------
__global__ __launch_bounds__(256) void vq_finalize(const double* __restrict__ partials,
                                                   const int* __restrict__ step_p,
                                                   float* __restrict__ out_loss) {
  const int t = threadIdx.x;
  double s = 0.0;
  for (int i = t; i < 4096; i += 256) s += partials[i];
  for (int o = 32; o; o >>= 1) s += __shfl_down(s, o);
  __shared__ double w4[4];
  if ((t & 63) == 0) w4[t >> 6] = s;
  __syncthreads();
  if (t == 0) {
    const double total = (w4[0] + w4[1]) + (w4[2] + w4[3]);
    const int step = step_p[0];
    double beta = 1.0;
    if (step < 1000) {
      double r = (double)step / 1000.0;
      beta = 0.01 + 0.99 * r * r;
    }
    const float m = (float)(total / ((double)NROW * (double)DDIM));
    out_loss[0] = m + (float)beta * m;  // mean1 + beta*mean2, mean1==mean2
  }
}

// ---------------------------------------------------------------------------
extern "C" void kernel_launch(void* const* d_in, const int* in_sizes, int n_in,
                              void* d_out, int out_size, void* d_ws, size_t ws_size,
                              hipStream_t stream) {
  (void)in_sizes;
  (void)n_in;
  (void)out_size;
  (void)ws_size;
  const float* z = (const float*)d_in[0];
  const float* cb = (const float*)d_in[1];
  const int* step = (const int*)d_in[2];

  float* out = (float*)d_out;
  float* zq = out + 1;
  float* oidx = out + 1 + (size_t)NROW * DDIM;

  // ws layout (all 16B-aligned where needed): c2 | chi | clo | partials
  char* w = (char*)d_ws;
  float* c2 = (float*)w;                              // 4 KiB
  _Float16* chi = (_Float16*)(w + 4096);              // 512 KiB
  _Float16* clo = (_Float16*)(w + 4096 + 524288);     // 512 KiB
  double* partials = (double*)(w + 4096 + 1048576);   // 32 KiB

  vq_prep<<<KCODE, 256, 0, stream>>>(cb, c2, chi, clo);
  vq_gemm_argmin<<<GBLK, 512, 0, stream>>>(z, chi, clo, c2, oidx);
  vq_gather<<<4096, 256, 0, stream>>>(z, cb, oidx, zq, partials);
  vq_finalize<<<1, 256, 0, stream>>>(partials, step, out);
}